// Round 5
// baseline (343.012 us; speedup 1.0000x reference)
//
#include <hip/hip_runtime.h>
#include <hip/hip_bf16.h>
#include <math.h>

#define NT 32
#define NSTEP 31
#define DD 384
#define HH 128
#define KK 128
#define MBATCH 8
#define NPIX 65536   // 256*256

typedef float f32x4 __attribute__((ext_vector_type(4)));
typedef short bf16x8 __attribute__((ext_vector_type(8)));

__device__ __forceinline__ unsigned short f2bf(float f) {
  unsigned u = __float_as_uint(f);
  return (unsigned short)((u + 0x7FFFu + ((u >> 16) & 1u)) >> 16);  // RNE
}
__device__ __forceinline__ unsigned pk2(float a, float b) {
  return (unsigned)f2bf(a) | ((unsigned)f2bf(b) << 16);
}

// ---------------- Kernel 1: serial RK4 (3/8 rule) ODE, 1 block, MFMA MLP ----
// 12 barrier-phases per step (L1,L2,L3 x 4 stages). RK combiner and y-update
// are folded into L3's epilogue (owner lanes hold k_s rows in registers).
// coeffT global stores are deferred across a barrier to hide the vmcnt drain.
__global__ __launch_bounds__(512, 1) void ode_kernel(
    const float* __restrict__ tarr, const float* __restrict__ ic,
    const float* __restrict__ W1, const float* __restrict__ b1,
    const float* __restrict__ W2, const float* __restrict__ b2,
    const float* __restrict__ W3, const float* __restrict__ b3,
    float* __restrict__ coeffT)   // [3][128][32] = [c][k][t]
{
  __shared__ bf16x8 sh_w1[8 * 12 * 64];                  // 96 KB: [w][chunk][lane]
  __shared__ __align__(16) float sh_y[DD];
  __shared__ __align__(16) float sh_k[4][DD];
  __shared__ __align__(16) float sh_b1[HH], sh_b2[HH], sh_b3[DD];
  __shared__ float sh_t[NT];
  __shared__ __align__(16) unsigned short sh_x[DD];      // bf16 MLP input
  __shared__ __align__(16) unsigned sh_h1u[HH / 2];      // bf16 h1 (packed)
  __shared__ __align__(16) unsigned sh_h2u[HH / 2];      // bf16 h2 (packed)

  const int tid = threadIdx.x;
  const int w = tid >> 6, l = tid & 63;
  const int r16 = l & 15, g = l >> 4;

  for (int i = tid; i < HH; i += 512) { sh_b1[i] = b1[i]; sh_b2[i] = b2[i]; }
  for (int i = tid; i < DD; i += 512) {
    sh_b3[i] = b3[i];
    float y0 = ic[i];
    sh_y[i] = y0;
    sh_x[i] = f2bf(y0);
    coeffT[(i % 3) * (KK * NT) + (i / 3) * NT + 0] = y0;  // t = 0
  }
  if (tid < NT) sh_t[tid] = tarr[tid];

  // ---- build W1 fragments into LDS: frag(w',c)[lane] elem j =
  //      bf16(W1[16w' + (lane&15)][32c + 8*(lane>>4) + j])
  for (int idx = tid; idx < 8 * 12 * 64; idx += 512) {
    const int lw = idx & 63, tmp = idx >> 6;
    const int c = tmp % 12, ww = tmp / 12;
    const float* src = W1 + (16 * ww + (lw & 15)) * DD + 32 * c + 8 * (lw >> 4);
    bf16x8 v;
    #pragma unroll
    for (int j = 0; j < 8; ++j) v[j] = (short)f2bf(src[j]);
    sh_w1[idx] = v;
  }

  // ---- W2/W3 fragments in registers (bf16-packed, 16 + 48 VGPRs) ----
  bf16x8 w2f[4], w3f[3][4];
  #pragma unroll
  for (int c = 0; c < 4; ++c) {
    const float* src = W2 + (16 * w + r16) * HH + 32 * c + 8 * g;
    #pragma unroll
    for (int j = 0; j < 8; ++j) w2f[c][j] = (short)f2bf(src[j]);
  }
  #pragma unroll
  for (int t = 0; t < 3; ++t)
    #pragma unroll
    for (int c = 0; c < 4; ++c) {
      const float* src = W3 + (48 * w + 16 * t + r16) * HH + 32 * c + 8 * g;
      #pragma unroll
      for (int j = 0; j < 8; ++j) w3f[t][c][j] = (short)f2bf(src[j]);
    }

  // deferred coeff values (owner lanes r16==0: rows 48w+16t3+4g+j)
  float ynew[3][4];

  __syncthreads();

  for (int step = 0; step < NSTEP; ++step) {
    const float dt  = sh_t[step + 1] - sh_t[step];
    const float dt3 = dt * (1.0f / 3.0f);

    // ---- deferred global store of previous step's y (coeff t = step) ----
    if (step > 0 && r16 == 0) {
      #pragma unroll
      for (int t3 = 0; t3 < 3; ++t3) {
        const int row0 = 48 * w + 16 * t3 + 4 * g;
        #pragma unroll
        for (int j = 0; j < 4; ++j) {
          const int row = row0 + j;
          coeffT[(row % 3) * (KK * NT) + (row / 3) * NT + step] = ynew[t3][j];
        }
      }
    }

    #pragma unroll
    for (int s = 0; s < 4; ++s) {
      // ---- L1: h1 = relu(W1 x + b1)  (12 MFMA, 4 chains) ----
      {
        f32x4 a0 = {0.f,0.f,0.f,0.f}, a1 = {0.f,0.f,0.f,0.f};
        f32x4 a2 = {0.f,0.f,0.f,0.f}, a3 = {0.f,0.f,0.f,0.f};
        #pragma unroll
        for (int c = 0; c < 12; c += 4) {
          bf16x8 A0 = sh_w1[(w * 12 + c + 0) * 64 + l];
          bf16x8 B0 = *(const bf16x8*)&sh_x[(c + 0) * 32 + g * 8];
          a0 = __builtin_amdgcn_mfma_f32_16x16x32_bf16(A0, B0, a0, 0, 0, 0);
          bf16x8 A1 = sh_w1[(w * 12 + c + 1) * 64 + l];
          bf16x8 B1 = *(const bf16x8*)&sh_x[(c + 1) * 32 + g * 8];
          a1 = __builtin_amdgcn_mfma_f32_16x16x32_bf16(A1, B1, a1, 0, 0, 0);
          bf16x8 A2 = sh_w1[(w * 12 + c + 2) * 64 + l];
          bf16x8 B2 = *(const bf16x8*)&sh_x[(c + 2) * 32 + g * 8];
          a2 = __builtin_amdgcn_mfma_f32_16x16x32_bf16(A2, B2, a2, 0, 0, 0);
          bf16x8 A3 = sh_w1[(w * 12 + c + 3) * 64 + l];
          bf16x8 B3 = *(const bf16x8*)&sh_x[(c + 3) * 32 + g * 8];
          a3 = __builtin_amdgcn_mfma_f32_16x16x32_bf16(A3, B3, a3, 0, 0, 0);
        }
        if (r16 == 0) {
          f32x4 bv = *(const f32x4*)&sh_b1[16 * w + 4 * g];
          float h0 = fmaxf(a0[0] + a1[0] + a2[0] + a3[0] + bv[0], 0.f);
          float h1_ = fmaxf(a0[1] + a1[1] + a2[1] + a3[1] + bv[1], 0.f);
          float h2_ = fmaxf(a0[2] + a1[2] + a2[2] + a3[2] + bv[2], 0.f);
          float h3 = fmaxf(a0[3] + a1[3] + a2[3] + a3[3] + bv[3], 0.f);
          const int base = (16 * w + 4 * g) >> 1;
          sh_h1u[base]     = pk2(h0, h1_);
          sh_h1u[base + 1] = pk2(h2_, h3);
        }
      }
      __syncthreads();

      // ---- L2: h2 = elu(W2 h1 + b2)  (4 MFMA, 2 chains) ----
      {
        f32x4 acc0 = {0.f,0.f,0.f,0.f}, acc1 = {0.f,0.f,0.f,0.f};
        acc0 = __builtin_amdgcn_mfma_f32_16x16x32_bf16(
            w2f[0], *(const bf16x8*)&sh_h1u[0 * 16 + g * 4], acc0, 0, 0, 0);
        acc1 = __builtin_amdgcn_mfma_f32_16x16x32_bf16(
            w2f[1], *(const bf16x8*)&sh_h1u[1 * 16 + g * 4], acc1, 0, 0, 0);
        acc0 = __builtin_amdgcn_mfma_f32_16x16x32_bf16(
            w2f[2], *(const bf16x8*)&sh_h1u[2 * 16 + g * 4], acc0, 0, 0, 0);
        acc1 = __builtin_amdgcn_mfma_f32_16x16x32_bf16(
            w2f[3], *(const bf16x8*)&sh_h1u[3 * 16 + g * 4], acc1, 0, 0, 0);
        if (r16 == 0) {
          f32x4 bv = *(const f32x4*)&sh_b2[16 * w + 4 * g];
          float v0 = acc0[0] + acc1[0] + bv[0]; v0 = v0 > 0.f ? v0 : expm1f(v0);
          float v1 = acc0[1] + acc1[1] + bv[1]; v1 = v1 > 0.f ? v1 : expm1f(v1);
          float v2 = acc0[2] + acc1[2] + bv[2]; v2 = v2 > 0.f ? v2 : expm1f(v2);
          float v3 = acc0[3] + acc1[3] + bv[3]; v3 = v3 > 0.f ? v3 : expm1f(v3);
          const int base = (16 * w + 4 * g) >> 1;
          sh_h2u[base]     = pk2(v0, v1);
          sh_h2u[base + 1] = pk2(v2, v3);
        }
      }
      __syncthreads();

      // ---- L3: k_s = W3 h2 + b3, + folded RK combiner / y-update ----
      {
        bf16x8 bb0 = *(const bf16x8*)&sh_h2u[0 * 16 + g * 4];
        bf16x8 bb1 = *(const bf16x8*)&sh_h2u[1 * 16 + g * 4];
        bf16x8 bb2 = *(const bf16x8*)&sh_h2u[2 * 16 + g * 4];
        bf16x8 bb3 = *(const bf16x8*)&sh_h2u[3 * 16 + g * 4];
        f32x4 ka[3];
        #pragma unroll
        for (int t3 = 0; t3 < 3; ++t3) {
          f32x4 acc = {0.f, 0.f, 0.f, 0.f};
          acc = __builtin_amdgcn_mfma_f32_16x16x32_bf16(w3f[t3][0], bb0, acc, 0, 0, 0);
          acc = __builtin_amdgcn_mfma_f32_16x16x32_bf16(w3f[t3][1], bb1, acc, 0, 0, 0);
          acc = __builtin_amdgcn_mfma_f32_16x16x32_bf16(w3f[t3][2], bb2, acc, 0, 0, 0);
          acc = __builtin_amdgcn_mfma_f32_16x16x32_bf16(w3f[t3][3], bb3, acc, 0, 0, 0);
          ka[t3] = acc;
        }
        if (r16 == 0) {
          #pragma unroll
          for (int t3 = 0; t3 < 3; ++t3) {
            const int row0 = 48 * w + 16 * t3 + 4 * g;
            f32x4 bv = *(const f32x4*)&sh_b3[row0];
            f32x4 kv;
            kv[0] = ka[t3][0] + bv[0]; kv[1] = ka[t3][1] + bv[1];
            kv[2] = ka[t3][2] + bv[2]; kv[3] = ka[t3][3] + bv[3];
            *(f32x4*)&sh_k[s][row0] = kv;

            f32x4 yv = *(const f32x4*)&sh_y[row0];
            if (s == 0) {
              float x0 = fmaf(dt3, kv[0], yv[0]);
              float x1 = fmaf(dt3, kv[1], yv[1]);
              float x2 = fmaf(dt3, kv[2], yv[2]);
              float x3 = fmaf(dt3, kv[3], yv[3]);
              *(uint2*)&sh_x[row0] = make_uint2(pk2(x0, x1), pk2(x2, x3));
            } else if (s == 1) {
              f32x4 k0 = *(const f32x4*)&sh_k[0][row0];
              float x0 = fmaf(dt, kv[0] - (1.0f/3.0f) * k0[0], yv[0]);
              float x1 = fmaf(dt, kv[1] - (1.0f/3.0f) * k0[1], yv[1]);
              float x2 = fmaf(dt, kv[2] - (1.0f/3.0f) * k0[2], yv[2]);
              float x3 = fmaf(dt, kv[3] - (1.0f/3.0f) * k0[3], yv[3]);
              *(uint2*)&sh_x[row0] = make_uint2(pk2(x0, x1), pk2(x2, x3));
            } else if (s == 2) {
              f32x4 k0 = *(const f32x4*)&sh_k[0][row0];
              f32x4 k1 = *(const f32x4*)&sh_k[1][row0];
              float x0 = fmaf(dt, k0[0] - k1[0] + kv[0], yv[0]);
              float x1 = fmaf(dt, k0[1] - k1[1] + kv[1], yv[1]);
              float x2 = fmaf(dt, k0[2] - k1[2] + kv[2], yv[2]);
              float x3 = fmaf(dt, k0[3] - k1[3] + kv[3], yv[3]);
              *(uint2*)&sh_x[row0] = make_uint2(pk2(x0, x1), pk2(x2, x3));
            } else {
              f32x4 k0 = *(const f32x4*)&sh_k[0][row0];
              f32x4 k1 = *(const f32x4*)&sh_k[1][row0];
              f32x4 k2 = *(const f32x4*)&sh_k[2][row0];
              const float c8 = dt * 0.125f;
              float y0n = fmaf(c8, k0[0] + 3.f * (k1[0] + k2[0]) + kv[0], yv[0]);
              float y1n = fmaf(c8, k0[1] + 3.f * (k1[1] + k2[1]) + kv[1], yv[1]);
              float y2n = fmaf(c8, k0[2] + 3.f * (k1[2] + k2[2]) + kv[2], yv[2]);
              float y3n = fmaf(c8, k0[3] + 3.f * (k1[3] + k2[3]) + kv[3], yv[3]);
              ynew[t3][0] = y0n; ynew[t3][1] = y1n;
              ynew[t3][2] = y2n; ynew[t3][3] = y3n;
              *(f32x4*)&sh_y[row0] = *(const f32x4*)&ynew[t3][0];
              *(uint2*)&sh_x[row0] = make_uint2(pk2(y0n, y1n), pk2(y2n, y3n));
            }
          }
        }
      }
      __syncthreads();
    } // stages
  } // steps

  // final coeff store (t = 31)
  if (r16 == 0) {
    #pragma unroll
    for (int t3 = 0; t3 < 3; ++t3) {
      const int row0 = 48 * w + 16 * t3 + 4 * g;
      #pragma unroll
      for (int j = 0; j < 4; ++j) {
        const int row = row0 + j;
        coeffT[(row % 3) * (KK * NT) + (row / 3) * NT + NSTEP] = ynew[t3][j];
      }
    }
  }
}

// ---------------- Kernel 2: out[t,m,c,p] = sum_k coeffT[c][k][t]*basis[k,c,p]
__global__ __launch_bounds__(256, 4) void einsum_kernel(
    const float* __restrict__ basis, const float* __restrict__ coeffT,
    float* __restrict__ out)
{
  __shared__ __align__(16) float sh_c[KK * NT];  // [k][t] for this c, 16KB
  const int tid = threadIdx.x;
  const int bid = blockIdx.x;
  const int c = bid >> 8;        // 0..2
  const int ptile = bid & 255;   // 0..255, 256 pixels each

  const float* cT = coeffT + c * (KK * NT);
  #pragma unroll
  for (int q = 0; q < 4; ++q)
    *(float4*)&sh_c[tid * 16 + q * 4] = *(const float4*)&cT[tid * 16 + q * 4];
  __syncthreads();

  const int slot = tid & 31;   // 32 slots x 8 px = 256 px
  const int tg   = tid >> 5;   // 8 groups x 4 t  = 32 t
  const int px0  = ptile * 256 + slot * 8;
  const float* bp = basis + (size_t)c * NPIX + px0;

  float acc[4][8];
  #pragma unroll
  for (int t = 0; t < 4; ++t)
    #pragma unroll
    for (int p = 0; p < 8; ++p) acc[t][p] = 0.f;

  #pragma unroll 4
  for (int k = 0; k < KK; ++k) {
    const float* bk = bp + (size_t)k * (3 * NPIX);
    float4 b0 = *(const float4*)(bk);
    float4 b1v = *(const float4*)(bk + 4);
    float4 cv = *(const float4*)&sh_c[k * NT + tg * 4];
    float cs[4] = {cv.x, cv.y, cv.z, cv.w};
    float bs[8] = {b0.x, b0.y, b0.z, b0.w, b1v.x, b1v.y, b1v.z, b1v.w};
    #pragma unroll
    for (int t = 0; t < 4; ++t)
      #pragma unroll
      for (int p = 0; p < 8; ++p)
        acc[t][p] = fmaf(cs[t], bs[p], acc[t][p]);
  }

  #pragma unroll
  for (int t = 0; t < 4; ++t) {
    const int tt = tg * 4 + t;
    #pragma unroll
    for (int m = 0; m < MBATCH; ++m) {
      float* op = out + (((size_t)(tt * MBATCH + m) * 3 + c) << 16) + px0;
      *(float4*)(op)     = make_float4(acc[t][0], acc[t][1], acc[t][2], acc[t][3]);
      *(float4*)(op + 4) = make_float4(acc[t][4], acc[t][5], acc[t][6], acc[t][7]);
    }
  }
}

extern "C" void kernel_launch(void* const* d_in, const int* in_sizes, int n_in,
                              void* d_out, int out_size, void* d_ws, size_t ws_size,
                              hipStream_t stream) {
  (void)in_sizes; (void)n_in; (void)out_size; (void)ws_size;
  // setup_inputs order: grid0, t, init_coeffs, W1, b1, W2, b2, W3, b3, basis
  const float* tarr  = (const float*)d_in[1];
  const float* ic    = (const float*)d_in[2];
  const float* W1    = (const float*)d_in[3];
  const float* b1    = (const float*)d_in[4];
  const float* W2    = (const float*)d_in[5];
  const float* b2    = (const float*)d_in[6];
  const float* W3    = (const float*)d_in[7];
  const float* b3    = (const float*)d_in[8];
  const float* basis = (const float*)d_in[9];
  float* coeffT = (float*)d_ws;          // 3*128*32 floats = 48 KB
  float* out    = (float*)d_out;

  hipLaunchKernelGGL(ode_kernel, dim3(1), dim3(512), 0, stream,
                     tarr, ic, W1, b1, W2, b2, W3, b3, coeffT);
  hipLaunchKernelGGL(einsum_kernel, dim3(768), dim3(256), 0, stream,
                     basis, coeffT, out);
}

// Round 6
// 304.029 us; speedup vs baseline: 1.1282x; 1.1282x over previous
//
#include <hip/hip_runtime.h>
#include <hip/hip_bf16.h>
#include <math.h>

#define NT 32
#define NSTEP 31
#define DD 384
#define HH 128
#define KK 128
#define MBATCH 8
#define NPIX 65536   // 256*256

typedef float f32x4 __attribute__((ext_vector_type(4)));
typedef short bf16x8 __attribute__((ext_vector_type(8)));

__device__ __forceinline__ unsigned short f2bf(float f) {
  unsigned u = __float_as_uint(f);
  return (unsigned short)((u + 0x7FFFu + ((u >> 16) & 1u)) >> 16);  // RNE
}
__device__ __forceinline__ unsigned pk2(float a, float b) {
  return (unsigned)f2bf(a) | ((unsigned)f2bf(b) << 16);
}
__device__ __forceinline__ float bflo(unsigned u) { return __uint_as_float(u << 16); }
__device__ __forceinline__ float bfhi(unsigned u) { return __uint_as_float(u & 0xFFFF0000u); }

// ---------------- Kernel 1: serial RK4 (3/8 rule) ODE, 1 block, MFMA MLP ----
// 12 barrier-phases/step. Key fact: the MFMA D-fragment is replicated across
// the 16 column-lanes (B operand is broadcast), so after L3 every lane holds
// its 12 k-values in REGISTERS. y (fp32) and k1..k3 (bf16-packed) stay in
// registers; the RK combiner runs in-register on all lanes (no LDS reads).
// LDS traffic per phase is only: W1/h fragments in, one packed vector out.
__global__ __launch_bounds__(512, 1) void ode_kernel(
    const float* __restrict__ tarr, const float* __restrict__ ic,
    const float* __restrict__ W1, const float* __restrict__ b1,
    const float* __restrict__ W2, const float* __restrict__ b2,
    const float* __restrict__ W3, const float* __restrict__ b3,
    float* __restrict__ coeffT)   // [3][128][32] = [c][k][t]
{
  __shared__ bf16x8 sh_w1[8 * 12 * 64];                  // 96 KB: [w][chunk][lane]
  __shared__ __align__(16) float sh_b1[HH], sh_b2[HH], sh_b3[DD];
  __shared__ float sh_t[NT];
  __shared__ __align__(16) unsigned short sh_x[DD];      // bf16 MLP input
  __shared__ __align__(16) unsigned sh_h1u[HH / 2];      // bf16 h1 (packed)
  __shared__ __align__(16) unsigned sh_h2u[HH / 2];      // bf16 h2 (packed)

  const int tid = threadIdx.x;
  const int w = tid >> 6, l = tid & 63;
  const int r16 = l & 15, g = l >> 4;

  for (int i = tid; i < HH; i += 512) { sh_b1[i] = b1[i]; sh_b2[i] = b2[i]; }
  for (int i = tid; i < DD; i += 512) {
    sh_b3[i] = b3[i];
    float y0 = ic[i];
    sh_x[i] = f2bf(y0);
    coeffT[(i % 3) * (KK * NT) + (i / 3) * NT + 0] = y0;  // t = 0
  }
  if (tid < NT) sh_t[tid] = tarr[tid];

  // ---- build W1 fragments into LDS ----
  for (int idx = tid; idx < 8 * 12 * 64; idx += 512) {
    const int lw = idx & 63, tmp = idx >> 6;
    const int c = tmp % 12, ww = tmp / 12;
    const float* src = W1 + (16 * ww + (lw & 15)) * DD + 32 * c + 8 * (lw >> 4);
    bf16x8 v;
    #pragma unroll
    for (int j = 0; j < 8; ++j) v[j] = (short)f2bf(src[j]);
    sh_w1[idx] = v;
  }

  // ---- W2/W3 fragments in registers (bf16-packed, 16 + 48 VGPRs) ----
  bf16x8 w2f[4], w3f[3][4];
  #pragma unroll
  for (int c = 0; c < 4; ++c) {
    const float* src = W2 + (16 * w + r16) * HH + 32 * c + 8 * g;
    #pragma unroll
    for (int j = 0; j < 8; ++j) w2f[c][j] = (short)f2bf(src[j]);
  }
  #pragma unroll
  for (int t3 = 0; t3 < 3; ++t3)
    #pragma unroll
    for (int c = 0; c < 4; ++c) {
      const float* src = W3 + (48 * w + 16 * t3 + r16) * HH + 32 * c + 8 * g;
      #pragma unroll
      for (int j = 0; j < 8; ++j) w3f[t3][c][j] = (short)f2bf(src[j]);
    }

  // ---- ODE state y in registers (every lane holds its 12 rows; values are
  //      replicated across the 16 lanes sharing g) ----
  float yr[3][4];
  #pragma unroll
  for (int t3 = 0; t3 < 3; ++t3) {
    const float* p = ic + 48 * w + 16 * t3 + 4 * g;
    #pragma unroll
    for (int r = 0; r < 4; ++r) yr[t3][r] = p[r];
  }

  unsigned k0p[3][2], k1p[3][2], k2p[3][2];  // bf16-packed k1,k2,k3

  __syncthreads();

  for (int step = 0; step < NSTEP; ++step) {
    const float dt  = sh_t[step + 1] - sh_t[step];
    const float dt3 = dt * (1.0f / 3.0f);

    // ---- deferred global store of coeff t = step (y == y_step here);
    //      drains at a barrier ~an L1-phase later, hiding store latency ----
    if (step > 0 && r16 == 0) {
      #pragma unroll
      for (int t3 = 0; t3 < 3; ++t3)
        #pragma unroll
        for (int j = 0; j < 4; ++j) {
          const int row = 48 * w + 16 * t3 + 4 * g + j;
          coeffT[(row % 3) * (KK * NT) + (row / 3) * NT + step] = yr[t3][j];
        }
    }

    #pragma unroll
    for (int s = 0; s < 4; ++s) {
      // ---- L1: h1 = relu(W1 x + b1)  (12 MFMA, 4 chains) ----
      {
        f32x4 a0 = {0.f,0.f,0.f,0.f}, a1 = {0.f,0.f,0.f,0.f};
        f32x4 a2 = {0.f,0.f,0.f,0.f}, a3 = {0.f,0.f,0.f,0.f};
        #pragma unroll
        for (int c = 0; c < 12; c += 4) {
          bf16x8 A0 = sh_w1[(w * 12 + c + 0) * 64 + l];
          bf16x8 B0 = *(const bf16x8*)&sh_x[(c + 0) * 32 + g * 8];
          a0 = __builtin_amdgcn_mfma_f32_16x16x32_bf16(A0, B0, a0, 0, 0, 0);
          bf16x8 A1 = sh_w1[(w * 12 + c + 1) * 64 + l];
          bf16x8 B1 = *(const bf16x8*)&sh_x[(c + 1) * 32 + g * 8];
          a1 = __builtin_amdgcn_mfma_f32_16x16x32_bf16(A1, B1, a1, 0, 0, 0);
          bf16x8 A2 = sh_w1[(w * 12 + c + 2) * 64 + l];
          bf16x8 B2 = *(const bf16x8*)&sh_x[(c + 2) * 32 + g * 8];
          a2 = __builtin_amdgcn_mfma_f32_16x16x32_bf16(A2, B2, a2, 0, 0, 0);
          bf16x8 A3 = sh_w1[(w * 12 + c + 3) * 64 + l];
          bf16x8 B3 = *(const bf16x8*)&sh_x[(c + 3) * 32 + g * 8];
          a3 = __builtin_amdgcn_mfma_f32_16x16x32_bf16(A3, B3, a3, 0, 0, 0);
        }
        if (r16 == 0) {
          f32x4 bv = *(const f32x4*)&sh_b1[16 * w + 4 * g];
          float h0 = fmaxf(a0[0] + a1[0] + a2[0] + a3[0] + bv[0], 0.f);
          float h1_ = fmaxf(a0[1] + a1[1] + a2[1] + a3[1] + bv[1], 0.f);
          float h2_ = fmaxf(a0[2] + a1[2] + a2[2] + a3[2] + bv[2], 0.f);
          float h3 = fmaxf(a0[3] + a1[3] + a2[3] + a3[3] + bv[3], 0.f);
          const int base = (16 * w + 4 * g) >> 1;
          sh_h1u[base]     = pk2(h0, h1_);
          sh_h1u[base + 1] = pk2(h2_, h3);
        }
      }
      __syncthreads();

      // ---- L2: h2 = elu(W2 h1 + b2)  (4 MFMA, 2 chains) ----
      {
        f32x4 acc0 = {0.f,0.f,0.f,0.f}, acc1 = {0.f,0.f,0.f,0.f};
        acc0 = __builtin_amdgcn_mfma_f32_16x16x32_bf16(
            w2f[0], *(const bf16x8*)&sh_h1u[0 * 16 + g * 4], acc0, 0, 0, 0);
        acc1 = __builtin_amdgcn_mfma_f32_16x16x32_bf16(
            w2f[1], *(const bf16x8*)&sh_h1u[1 * 16 + g * 4], acc1, 0, 0, 0);
        acc0 = __builtin_amdgcn_mfma_f32_16x16x32_bf16(
            w2f[2], *(const bf16x8*)&sh_h1u[2 * 16 + g * 4], acc0, 0, 0, 0);
        acc1 = __builtin_amdgcn_mfma_f32_16x16x32_bf16(
            w2f[3], *(const bf16x8*)&sh_h1u[3 * 16 + g * 4], acc1, 0, 0, 0);
        if (r16 == 0) {
          f32x4 bv = *(const f32x4*)&sh_b2[16 * w + 4 * g];
          float v0 = acc0[0] + acc1[0] + bv[0]; v0 = v0 > 0.f ? v0 : expm1f(v0);
          float v1 = acc0[1] + acc1[1] + bv[1]; v1 = v1 > 0.f ? v1 : expm1f(v1);
          float v2 = acc0[2] + acc1[2] + bv[2]; v2 = v2 > 0.f ? v2 : expm1f(v2);
          float v3 = acc0[3] + acc1[3] + bv[3]; v3 = v3 > 0.f ? v3 : expm1f(v3);
          const int base = (16 * w + 4 * g) >> 1;
          sh_h2u[base]     = pk2(v0, v1);
          sh_h2u[base + 1] = pk2(v2, v3);
        }
      }
      __syncthreads();

      // ---- L3: k_s = W3 h2 + b3, combiner fully in registers (all lanes) ----
      {
        // issue bias reads first (broadcast; latency hidden under MFMAs)
        f32x4 bv0 = *(const f32x4*)&sh_b3[48 * w +  0 + 4 * g];
        f32x4 bv1 = *(const f32x4*)&sh_b3[48 * w + 16 + 4 * g];
        f32x4 bv2 = *(const f32x4*)&sh_b3[48 * w + 32 + 4 * g];
        bf16x8 bb0 = *(const bf16x8*)&sh_h2u[0 * 16 + g * 4];
        bf16x8 bb1 = *(const bf16x8*)&sh_h2u[1 * 16 + g * 4];
        bf16x8 bb2 = *(const bf16x8*)&sh_h2u[2 * 16 + g * 4];
        bf16x8 bb3 = *(const bf16x8*)&sh_h2u[3 * 16 + g * 4];
        f32x4 kv[3];
        #pragma unroll
        for (int t3 = 0; t3 < 3; ++t3) {
          f32x4 acc = {0.f, 0.f, 0.f, 0.f};
          acc = __builtin_amdgcn_mfma_f32_16x16x32_bf16(w3f[t3][0], bb0, acc, 0, 0, 0);
          acc = __builtin_amdgcn_mfma_f32_16x16x32_bf16(w3f[t3][1], bb1, acc, 0, 0, 0);
          acc = __builtin_amdgcn_mfma_f32_16x16x32_bf16(w3f[t3][2], bb2, acc, 0, 0, 0);
          acc = __builtin_amdgcn_mfma_f32_16x16x32_bf16(w3f[t3][3], bb3, acc, 0, 0, 0);
          kv[t3] = acc;
        }
        kv[0][0] += bv0[0]; kv[0][1] += bv0[1]; kv[0][2] += bv0[2]; kv[0][3] += bv0[3];
        kv[1][0] += bv1[0]; kv[1][1] += bv1[1]; kv[1][2] += bv1[2]; kv[1][3] += bv1[3];
        kv[2][0] += bv2[0]; kv[2][1] += bv2[1]; kv[2][2] += bv2[2]; kv[2][3] += bv2[3];

        unsigned xp[3][2];
        if (s == 0) {
          #pragma unroll
          for (int t3 = 0; t3 < 3; ++t3) {
            k0p[t3][0] = pk2(kv[t3][0], kv[t3][1]);
            k0p[t3][1] = pk2(kv[t3][2], kv[t3][3]);
            float x0 = fmaf(dt3, kv[t3][0], yr[t3][0]);
            float x1 = fmaf(dt3, kv[t3][1], yr[t3][1]);
            float x2 = fmaf(dt3, kv[t3][2], yr[t3][2]);
            float x3 = fmaf(dt3, kv[t3][3], yr[t3][3]);
            xp[t3][0] = pk2(x0, x1); xp[t3][1] = pk2(x2, x3);
          }
        } else if (s == 1) {
          #pragma unroll
          for (int t3 = 0; t3 < 3; ++t3) {
            k1p[t3][0] = pk2(kv[t3][0], kv[t3][1]);
            k1p[t3][1] = pk2(kv[t3][2], kv[t3][3]);
            float k00 = bflo(k0p[t3][0]), k01 = bfhi(k0p[t3][0]);
            float k02 = bflo(k0p[t3][1]), k03 = bfhi(k0p[t3][1]);
            float x0 = fmaf(dt, kv[t3][0] - (1.0f/3.0f) * k00, yr[t3][0]);
            float x1 = fmaf(dt, kv[t3][1] - (1.0f/3.0f) * k01, yr[t3][1]);
            float x2 = fmaf(dt, kv[t3][2] - (1.0f/3.0f) * k02, yr[t3][2]);
            float x3 = fmaf(dt, kv[t3][3] - (1.0f/3.0f) * k03, yr[t3][3]);
            xp[t3][0] = pk2(x0, x1); xp[t3][1] = pk2(x2, x3);
          }
        } else if (s == 2) {
          #pragma unroll
          for (int t3 = 0; t3 < 3; ++t3) {
            k2p[t3][0] = pk2(kv[t3][0], kv[t3][1]);
            k2p[t3][1] = pk2(kv[t3][2], kv[t3][3]);
            float k00 = bflo(k0p[t3][0]), k01 = bfhi(k0p[t3][0]);
            float k02 = bflo(k0p[t3][1]), k03 = bfhi(k0p[t3][1]);
            float k10 = bflo(k1p[t3][0]), k11 = bfhi(k1p[t3][0]);
            float k12 = bflo(k1p[t3][1]), k13 = bfhi(k1p[t3][1]);
            float x0 = fmaf(dt, k00 - k10 + kv[t3][0], yr[t3][0]);
            float x1 = fmaf(dt, k01 - k11 + kv[t3][1], yr[t3][1]);
            float x2 = fmaf(dt, k02 - k12 + kv[t3][2], yr[t3][2]);
            float x3 = fmaf(dt, k03 - k13 + kv[t3][3], yr[t3][3]);
            xp[t3][0] = pk2(x0, x1); xp[t3][1] = pk2(x2, x3);
          }
        } else {
          const float c8 = dt * 0.125f;
          #pragma unroll
          for (int t3 = 0; t3 < 3; ++t3) {
            float k00 = bflo(k0p[t3][0]), k01 = bfhi(k0p[t3][0]);
            float k02 = bflo(k0p[t3][1]), k03 = bfhi(k0p[t3][1]);
            float k10 = bflo(k1p[t3][0]), k11 = bfhi(k1p[t3][0]);
            float k12 = bflo(k1p[t3][1]), k13 = bfhi(k1p[t3][1]);
            float k20 = bflo(k2p[t3][0]), k21 = bfhi(k2p[t3][0]);
            float k22 = bflo(k2p[t3][1]), k23 = bfhi(k2p[t3][1]);
            yr[t3][0] = fmaf(c8, k00 + 3.f * (k10 + k20) + kv[t3][0], yr[t3][0]);
            yr[t3][1] = fmaf(c8, k01 + 3.f * (k11 + k21) + kv[t3][1], yr[t3][1]);
            yr[t3][2] = fmaf(c8, k02 + 3.f * (k12 + k22) + kv[t3][2], yr[t3][2]);
            yr[t3][3] = fmaf(c8, k03 + 3.f * (k13 + k23) + kv[t3][3], yr[t3][3]);
            xp[t3][0] = pk2(yr[t3][0], yr[t3][1]);
            xp[t3][1] = pk2(yr[t3][2], yr[t3][3]);
          }
        }
        if (r16 == 0) {
          #pragma unroll
          for (int t3 = 0; t3 < 3; ++t3)
            *(uint2*)&sh_x[48 * w + 16 * t3 + 4 * g] =
                make_uint2(xp[t3][0], xp[t3][1]);
        }
      }
      __syncthreads();
    } // stages
  } // steps

  // final coeff store (t = 31)
  if (r16 == 0) {
    #pragma unroll
    for (int t3 = 0; t3 < 3; ++t3)
      #pragma unroll
      for (int j = 0; j < 4; ++j) {
        const int row = 48 * w + 16 * t3 + 4 * g + j;
        coeffT[(row % 3) * (KK * NT) + (row / 3) * NT + NSTEP] = yr[t3][j];
      }
  }
}

// ---------------- Kernel 2: out[t,m,c,p] = sum_k coeffT[c][k][t]*basis[k,c,p]
__global__ __launch_bounds__(256, 4) void einsum_kernel(
    const float* __restrict__ basis, const float* __restrict__ coeffT,
    float* __restrict__ out)
{
  __shared__ __align__(16) float sh_c[KK * NT];  // [k][t] for this c, 16KB
  const int tid = threadIdx.x;
  const int bid = blockIdx.x;
  const int c = bid >> 8;        // 0..2
  const int ptile = bid & 255;   // 0..255, 256 pixels each

  const float* cT = coeffT + c * (KK * NT);
  #pragma unroll
  for (int q = 0; q < 4; ++q)
    *(float4*)&sh_c[tid * 16 + q * 4] = *(const float4*)&cT[tid * 16 + q * 4];
  __syncthreads();

  const int slot = tid & 31;   // 32 slots x 8 px = 256 px
  const int tg   = tid >> 5;   // 8 groups x 4 t  = 32 t
  const int px0  = ptile * 256 + slot * 8;
  const float* bp = basis + (size_t)c * NPIX + px0;

  float acc[4][8];
  #pragma unroll
  for (int t = 0; t < 4; ++t)
    #pragma unroll
    for (int p = 0; p < 8; ++p) acc[t][p] = 0.f;

  #pragma unroll 4
  for (int k = 0; k < KK; ++k) {
    const float* bk = bp + (size_t)k * (3 * NPIX);
    float4 b0 = *(const float4*)(bk);
    float4 b1v = *(const float4*)(bk + 4);
    float4 cv = *(const float4*)&sh_c[k * NT + tg * 4];
    float cs[4] = {cv.x, cv.y, cv.z, cv.w};
    float bs[8] = {b0.x, b0.y, b0.z, b0.w, b1v.x, b1v.y, b1v.z, b1v.w};
    #pragma unroll
    for (int t = 0; t < 4; ++t)
      #pragma unroll
      for (int p = 0; p < 8; ++p)
        acc[t][p] = fmaf(cs[t], bs[p], acc[t][p]);
  }

  #pragma unroll
  for (int t = 0; t < 4; ++t) {
    const int tt = tg * 4 + t;
    #pragma unroll
    for (int m = 0; m < MBATCH; ++m) {
      float* op = out + (((size_t)(tt * MBATCH + m) * 3 + c) << 16) + px0;
      *(float4*)(op)     = make_float4(acc[t][0], acc[t][1], acc[t][2], acc[t][3]);
      *(float4*)(op + 4) = make_float4(acc[t][4], acc[t][5], acc[t][6], acc[t][7]);
    }
  }
}

extern "C" void kernel_launch(void* const* d_in, const int* in_sizes, int n_in,
                              void* d_out, int out_size, void* d_ws, size_t ws_size,
                              hipStream_t stream) {
  (void)in_sizes; (void)n_in; (void)out_size; (void)ws_size;
  // setup_inputs order: grid0, t, init_coeffs, W1, b1, W2, b2, W3, b3, basis
  const float* tarr  = (const float*)d_in[1];
  const float* ic    = (const float*)d_in[2];
  const float* W1    = (const float*)d_in[3];
  const float* b1    = (const float*)d_in[4];
  const float* W2    = (const float*)d_in[5];
  const float* b2    = (const float*)d_in[6];
  const float* W3    = (const float*)d_in[7];
  const float* b3    = (const float*)d_in[8];
  const float* basis = (const float*)d_in[9];
  float* coeffT = (float*)d_ws;          // 3*128*32 floats = 48 KB
  float* out    = (float*)d_out;

  hipLaunchKernelGGL(ode_kernel, dim3(1), dim3(512), 0, stream,
                     tarr, ic, W1, b1, W2, b2, W3, b3, coeffT);
  hipLaunchKernelGGL(einsum_kernel, dim3(768), dim3(256), 0, stream,
                     basis, coeffT, out);
}